// Round 15
// baseline (137.949 us; speedup 1.0000x reference)
//
#include <hip/hip_runtime.h>

// ---------- types ----------
typedef _Float16 f16x8 __attribute__((ext_vector_type(8)));
typedef _Float16 f16x4 __attribute__((ext_vector_type(4)));
typedef _Float16 f16x2 __attribute__((ext_vector_type(2)));
typedef float    f32x4 __attribute__((ext_vector_type(4)));
typedef float    f32x16 __attribute__((ext_vector_type(16)));
typedef unsigned int u32x4 __attribute__((ext_vector_type(4)));
typedef unsigned short ushort_t;
typedef unsigned int uint_t;

#define LOG2E 1.44269504088896340736f

// counted-wait / barrier primitives (T4: loads stay in flight across barriers)
#define CFENCE  asm volatile("" ::: "memory")
#define HWBAR   __builtin_amdgcn_s_barrier()
#define VMCNT0  asm volatile("s_waitcnt vmcnt(0)" ::: "memory")
#define VMCNT3  asm volatile("s_waitcnt vmcnt(3)" ::: "memory")
#define VMCNT4  asm volatile("s_waitcnt vmcnt(4)" ::: "memory")

__device__ __forceinline__ ushort_t f2h(float x) {
  _Float16 h = (_Float16)x;
  return __builtin_bit_cast(ushort_t, h);
}

// raw v_exp_f32 (skips LLVM denormal-guard expansion; inputs in [-30,15]).
__device__ __forceinline__ float fexp2(float x) {
#if __has_builtin(__builtin_amdgcn_exp2f)
  return __builtin_amdgcn_exp2f(x);
#else
  float r; asm("v_exp_f32 %0, %1" : "=v"(r) : "v"(x)); return r;
#endif
}

// raw v_rsq_f32.
__device__ __forceinline__ float frsq(float x) {
#if __has_builtin(__builtin_amdgcn_rsqf)
  return __builtin_amdgcn_rsqf(x);
#else
  float r; asm("v_rsq_f32 %0, %1" : "=v"(r) : "v"(x)); return r;
#endif
}

__device__ __forceinline__ uint_t packpair(float a, float b) {
  return __builtin_bit_cast(uint_t, __builtin_amdgcn_cvt_pkrtz(a, b));
}

__device__ __forceinline__ f16x8 mk8(uint_t a, uint_t b, uint_t c, uint_t d) {
  u32x4 t; t[0] = a; t[1] = b; t[2] = c; t[3] = d;
  return __builtin_bit_cast(f16x8, t);
}

// async global->LDS, 16B per lane; LDS dest wave-uniform base + lane*16.
__device__ __forceinline__ void gload_lds16(const void* g, void* lds) {
  __builtin_amdgcn_global_load_lds(
      (const __attribute__((address_space(1))) void*)(uintptr_t)g,
      (__attribute__((address_space(3))) void*)(unsigned)(uintptr_t)lds,
      16, 0, 0);
}

// Fragment-major ("fm") for the GEMMs: granule (panel,kc) = 16 rows x K=32,
//   fm[(panel*24 + kc)*64 + l] (16B) = M[panel*16 + (l&15)][kc*32 + (l>>4)*8..+7]
// Granule-major for attention (32x32x16 frags, 1KB granules, lane-exact):
//   qbuf : [bh][qpanel 0..31][kch 0..3]   B-frag: lane = (q&31) + 32*((d>>3)&1)
//   kbuf : [bh][tile 0..15][rowp*4+dch]   A-frag: lane = (kv&31) + 32*((d>>3)&1)
//   vtb  : [bh][tile 0..15][dp*4+chunk]   A-frag: lane = (d&31) + 32*((slot>>3)&1)

// ---------- LocalRmsNorm: pass A (horizontal 7-tap box of x^2) -> f16 tmp ----------
__global__ __launch_bounds__(256)
void lrn_a(const float* __restrict__ x, ushort_t* __restrict__ tmp) {
  int tid = blockIdx.x * 256 + threadIdx.x;     // 8*1024*192 threads
  int dv  = tid % 192;
  int rem = tid / 192;
  int pos = rem & 1023;
  int b   = rem >> 10;
  int r = pos >> 5, c = pos & 31;
  const float4* base = (const float4*)x + ((size_t)b * 1024 + (size_t)r * 32) * 192 + dv;
  float ax = 0.f, ay = 0.f, az = 0.f, aw = 0.f;
#pragma unroll
  for (int dc = -3; dc <= 3; ++dc) {
    int cc = c + dc;
    if (cc >= 0 && cc < 32) {
      float4 v = base[cc * 192];
      ax += v.x * v.x; ay += v.y * v.y; az += v.z * v.z; aw += v.w * v.w;
    }
  }
  f16x4 o;
  o[0] = (_Float16)ax; o[1] = (_Float16)ay; o[2] = (_Float16)az; o[3] = (_Float16)aw;
  *(f16x4*)(tmp + (size_t)tid * 4) = o;
}

// ---------- LocalRmsNorm: pass B (vertical 7-tap) -> xn (f16, FRAGMENT-MAJOR) ----------
__global__ __launch_bounds__(256)
void lrn_b(const float* __restrict__ x, const ushort_t* __restrict__ tmp,
           const float* __restrict__ wn, ushort_t* __restrict__ xn) {
  int tid = blockIdx.x * 256 + threadIdx.x;
  int dv  = tid % 192;
  int rem = tid / 192;
  int pos = rem & 1023;
  int b   = rem >> 10;
  int r = pos >> 5, c = pos & 31;
  const ushort_t* tb = tmp + (((size_t)b * 1024 + c) * 192 + dv) * 4;
  float ax = 0.f, ay = 0.f, az = 0.f, aw = 0.f;
#pragma unroll
  for (int dr = -3; dr <= 3; ++dr) {
    int rr = r + dr;
    if (rr >= 0 && rr < 32) {
      f16x4 v = *(const f16x4*)(tb + (size_t)rr * 24576);
      ax += (float)v[0]; ay += (float)v[1]; az += (float)v[2]; aw += (float)v[3];
    }
  }
  float4 xv = ((const float4*)x)[tid];
  float4 wv = ((const float4*)wn)[dv];
  const float inv49 = 1.0f / 49.0f;
  float i0 = frsq(1e-7f + ax * inv49);
  float i1 = frsq(1e-7f + ay * inv49);
  float i2 = frsq(1e-7f + az * inv49);
  float i3 = frsq(1e-7f + aw * inv49);
  f16x4 o;
  o[0] = (_Float16)(xv.x * i0 * wv.x);
  o[1] = (_Float16)(xv.y * i1 * wv.y);
  o[2] = (_Float16)(xv.z * i2 * wv.z);
  o[3] = (_Float16)(xv.w * i3 * wv.w);
  const int m = b * 1024 + pos;
  const int panel = m >> 4, lrr = m & 15;
  const int kc = dv >> 3, lg2 = (dv >> 1) & 3, half = dv & 1;
  *(f16x4*)(xn + ((size_t)((panel * 24 + kc) * 64 + lg2 * 16 + lrr)) * 8 + half * 4) = o;
}

// ---------- weight conversion f32 -> f16 fragment-major ----------
__global__ __launch_bounds__(256)
void convw_fm(const float* __restrict__ wq, const float* __restrict__ wk,
              const float* __restrict__ wv, const float* __restrict__ wo,
              ushort_t* __restrict__ bqkv, ushort_t* __restrict__ bwo) {
  const int g = blockIdx.x * 256 + threadIdx.x;   // 294912 total
  const int mat = g / 73728;
  const int gg = g % 73728;
  const int panel = gg / 1536;
  const int rem = gg % 1536;
  const int kc = rem >> 6, l = rem & 63;
  const int row = panel * 16 + (l & 15);
  const int col = kc * 32 + (l >> 4) * 8;
  const float* src = (mat == 0) ? wq : (mat == 1) ? wk : (mat == 2) ? wv : wo;
  const float4 v0 = *(const float4*)(src + (size_t)row * 768 + col);
  const float4 v1 = *(const float4*)(src + (size_t)row * 768 + col + 4);
  f16x8 o;
  o[0]=(_Float16)v0.x; o[1]=(_Float16)v0.y; o[2]=(_Float16)v0.z; o[3]=(_Float16)v0.w;
  o[4]=(_Float16)v1.x; o[5]=(_Float16)v1.y; o[6]=(_Float16)v1.z; o[7]=(_Float16)v1.w;
  if (mat < 3) *(f16x8*)(bqkv + (size_t)g * 8) = o;
  else         *(f16x8*)(bwo  + (size_t)gg * 8) = o;
}

// ---------- GEMM: fm-granule LDS staging + counted-vmcnt (r8-proven protocol) ----------
// MODE 0: PM=8 PN=8 (128x128), grid 64x18 -> Q/K via epilogue LDS-transpose
//         (16B granule stores), V via direct 8B stores.
// MODE 1: PM=4 PN=8 (64x128), grid 128x6 -> fp32 row-major out.
#define GSTAGE(BUF, KT) do {                                                      \
    _Pragma("unroll")                                                             \
    for (int j = 0; j < SI; ++j)                                                  \
      gload_lds16(sb[j] + (KT) * 512, (BUF) ? d1[j] : d0[j]);                     \
  } while (0)

#define GTILE(KT, CUR, NXT) do {                                                  \
    CFENCE; HWBAR; CFENCE;                    /* prev-tile reads done */          \
    if ((KT) + 1 < 24) {                                                          \
      GSTAGE(NXT, (KT) + 1);                                                      \
      if constexpr (SI == 4) VMCNT4; else VMCNT3;   /* kt's granules landed */    \
    } else VMCNT0;                                                                \
    CFENCE; HWBAR;                            /* all waves' kt data visible */    \
    __builtin_amdgcn_sched_barrier(0);                                            \
    f16x8 af[MT], bf[NT];                                                         \
    _Pragma("unroll")                                                             \
    for (int mt = 0; mt < MT; ++mt)                                               \
      af[mt] = *(const f16x8*)(&smem[(CUR) * GR * 512 + (wr * MT + mt) * 512 + l * 8]); \
    _Pragma("unroll")                                                             \
    for (int nt = 0; nt < NT; ++nt)                                               \
      bf[nt] = *(const f16x8*)(&smem[(CUR) * GR * 512 + (PM + wc * NT + nt) * 512 + l * 8]); \
    _Pragma("unroll")                                                             \
    for (int mt = 0; mt < MT; ++mt)                                               \
      _Pragma("unroll")                                                           \
      for (int nt = 0; nt < NT; ++nt)                                             \
        acc[mt][nt] = __builtin_amdgcn_mfma_f32_16x16x32_f16(af[mt], bf[nt], acc[mt][nt], 0, 0, 0); \
  } while (0)

template <int MODE>
__global__ __launch_bounds__(256)
void gemm_lds(const ushort_t* __restrict__ Afm, const ushort_t* __restrict__ Bfm,
              const float* __restrict__ b0, const float* __restrict__ b1,
              const float* __restrict__ b2,
              ushort_t* __restrict__ q, ushort_t* __restrict__ k,
              ushort_t* __restrict__ v, float* __restrict__ outf) {
  constexpr int PM  = (MODE == 0) ? 8 : 4;     // A panels (16 rows each)
  constexpr int PN  = 8;                       // B panels
  constexpr int NBN = (MODE == 0) ? 18 : 6;
  constexpr int SI  = (PM + PN) / 4;           // stage instrs per wave
  constexpr int MT  = PM / 2, NT = PN / 2;
  constexpr int GR  = PM + PN;
  __shared__ __align__(16) ushort_t smem[2 * GR * 512];  // MODE0 32KB / MODE1 24KB

  const int nwg = gridDim.x;
  const int bid = blockIdx.x;
  const int cid = (bid & 7) * (nwg >> 3) + (bid >> 3);   // XCD-contiguous
  const int bm = cid / NBN, bn = cid % NBN;
  const int tid = threadIdx.x;
  const int w = tid >> 6, l = tid & 63;
  const int wr = w >> 1, wc = w & 1;
  const int lr = l & 15, lg = l >> 4;

  f32x4 acc[MT][NT] = {};

  // per-wave stage assignments: granule g = w*SI + j (A: 0..PM-1, B: PM..GR-1)
  const ushort_t* sb[SI];
  ushort_t* d0[SI];
  ushort_t* d1[SI];
#pragma unroll
  for (int j = 0; j < SI; ++j) {
    const int g = w * SI + j;
    if (g < PM) sb[j] = Afm + ((size_t)(bm * PM + g) * 24) * 512 + l * 8;
    else        sb[j] = Bfm + ((size_t)(bn * PN + (g - PM)) * 24) * 512 + l * 8;
    d0[j] = &smem[g * 512];
    d1[j] = &smem[GR * 512 + g * 512];
  }

  GSTAGE(0, 0);
  for (int kt = 0; kt < 24; kt += 2) {
    GTILE(kt, 0, 1);
    GTILE(kt + 1, 1, 0);
  }

  if (MODE == 0) {
    const int region = (bn * 128) / 768;       // block-uniform
    __syncthreads();                           // K-loop LDS reads done everywhere
    if (region == 2) {
      // ---- V: direct granule stores (already 8B-vectorized over gi) ----
#pragma unroll
      for (int mt = 0; mt < MT; ++mt) {
#pragma unroll
        for (int nt = 0; nt < NT; ++nt) {
          const int n = bn * 128 + wc * 64 + nt * 16 + lr;
          const int mbase = bm * 128 + wr * 64 + mt * 16 + lg * 4;
          const int nn = n - 1536;
          const int hh = nn >> 6, hd = nn & 63;
          const float bb = b2[nn];
          const int bi = mbase >> 10, s0 = mbase & 1023;
          const int tile = s0 >> 6, q6 = s0 & 63;
          const int aa = q6 >> 5, r5 = q6 & 31;
          const int t1 = r5 >> 3, h2 = (r5 >> 2) & 1;
          const int gq = t1 >> 1, jj = (2 * t1) & 3;
          const int chunk = (aa << 1) + gq;           // slot>>4
          const int gidx = (hd >> 5) * 4 + chunk;
          const int lane = (hd & 31) + 32 * h2;
          f16x4 pv;
#pragma unroll
          for (int gi = 0; gi < 4; ++gi) pv[gi] = (_Float16)(acc[mt][nt][gi] + bb);
          *(f16x4*)(v + (((size_t)(bi * 12 + hh) * 16 + tile) * 8 + gidx) * 512
                      + lane * 8 + 2 * jj) = pv;
        }
      }
    } else {
      // ---- Q/K: wave-private LDS transpose -> 16B coalesced granule stores ----
      const int nnb = bn * 128 - region * 768 + wc * 64;   // wave col base (mult of 64)
      const float* bptr = (region == 0) ? b0 : b1;
      const float qs = (region == 0) ? 0.125f * LOG2E : 1.0f;
      ushort_t* T = &smem[w * 4096];            // 8KB per wave, 4 waves = 32KB
#pragma unroll
      for (int nt = 0; nt < NT; ++nt) {
        const int col = nt * 16 + lr;
        const float bb = bptr[nnb + col];
#pragma unroll
        for (int mt = 0; mt < MT; ++mt)
#pragma unroll
          for (int gi = 0; gi < 4; ++gi) {
            const int row = mt * 16 + lg * 4 + gi;
            T[row * 64 + (((col >> 3) ^ (row & 7)) << 3) + (col & 7)] =
                f2h((acc[mt][nt][gi] + bb) * qs);
          }
      }
      // same-wave read-back (lgkmcnt ordering by compiler; no cross-wave access)
      const int m = bm * 128 + wr * 64 + l;
      const int bi = m >> 10, s = m & 1023;
      const int hh = nnb >> 6;
#pragma unroll
      for (int c8 = 0; c8 < 8; ++c8) {
        const f16x8 vv = *(const f16x8*)&T[l * 64 + ((c8 ^ (l & 7)) << 3)];
        const int kch = c8 >> 1, khalf = c8 & 1;
        const int lane = (s & 31) + 32 * khalf;
        if (region == 0)
          *(f16x8*)(q + (((size_t)(bi * 12 + hh) * 32 + (s >> 5)) * 4 + kch) * 512
                      + lane * 8) = vv;
        else
          *(f16x8*)(k + (((size_t)(bi * 12 + hh) * 16 + (s >> 6)) * 8
                         + ((s >> 5) & 1) * 4 + kch) * 512 + lane * 8) = vv;
      }
    }
  } else {
    // MODE 1: fp32 row-major out (lane-coalesced 4B stores)
#pragma unroll
    for (int mt = 0; mt < MT; ++mt)
#pragma unroll
      for (int nt = 0; nt < NT; ++nt) {
        const int n = bn * 128 + wc * 64 + nt * 16 + lr;
        const float bb = b0[n];
#pragma unroll
        for (int gi = 0; gi < 4; ++gi) {
          const int m = bm * 64 + wr * 32 + mt * 16 + lg * 4 + gi;
          outf[(size_t)m * 768 + n] = acc[mt][nt][gi] + bb;
        }
      }
  }
}

// ---------- fused flash attention: granule-major K/V/Q, conflict-free LDS ----------
#define ATILE(T, CUR, NXT) do {                                                   \
    CFENCE; HWBAR; CFENCE;                   /* prev-tile reads done */           \
    if ((T) < 15) {                                                               \
      const ushort_t* ksrc = kp + (size_t)((T) + 1) * 4096;                       \
      const ushort_t* vsrc = vp + (size_t)((T) + 1) * 4096;                       \
      gload_lds16(ksrc + tid * 8,           Kl0 + (NXT) * 8192);                  \
      gload_lds16(ksrc + (tid + 256) * 8,   Kl1 + (NXT) * 8192);                  \
      gload_lds16(vsrc + tid * 8,           Vl0 + (NXT) * 8192);                  \
      gload_lds16(vsrc + (tid + 256) * 8,   Vl1 + (NXT) * 8192);                  \
      VMCNT4;                                /* tile T's 4 loads landed */        \
    } else VMCNT0;                                                                \
    CFENCE; HWBAR;                           /* all waves' tile-T data visible */ \
    __builtin_amdgcn_sched_barrier(0);                                            \
    const char* kbase = (const char*)asmem + (CUR) * 8192;                        \
    const char* vbase = (const char*)asmem + 16384 + (CUR) * 8192;                \
    f16x8 ka0[4], ka1[4];                                                         \
    _Pragma("unroll")                                                             \
    for (int kc = 0; kc < 4; ++kc) {                                              \
      ka0[kc] = *(const f16x8*)(kbase + kc * 1024 + l * 16);                      \
      ka1[kc] = *(const f16x8*)(kbase + 4096 + kc * 1024 + l * 16);               \
    }                                                                             \
    f32x16 s0v = {}, s1v = {};                                                    \
    __builtin_amdgcn_s_setprio(1);                                                \
    _Pragma("unroll")                                                             \
    for (int kc = 0; kc < 4; ++kc) {                                              \
      s0v = __builtin_amdgcn_mfma_f32_32x32x16_f16(ka0[kc], qf[kc], s0v, 0, 0, 0);\
      s1v = __builtin_amdgcn_mfma_f32_32x32x16_f16(ka1[kc], qf[kc], s1v, 0, 0, 0);\
    }                                                                             \
    __builtin_amdgcn_s_setprio(0);                                                \
    f16x8 va0[4], va1[4];                                                         \
    _Pragma("unroll")                                                             \
    for (int c = 0; c < 4; ++c) {                                                 \
      va0[c] = *(const f16x8*)(vbase + c * 1024 + l * 16);                        \
      va1[c] = *(const f16x8*)(vbase + 4096 + c * 1024 + l * 16);                 \
    }                                                                             \
    uint_t pk0[8], pk1[8];                                                        \
    _Pragma("unroll")                                                             \
    for (int tt = 0; tt < 8; ++tt) {                                              \
      pk0[tt] = packpair(fexp2(s0v[2 * tt]), fexp2(s0v[2 * tt + 1]));             \
      pk1[tt] = packpair(fexp2(s1v[2 * tt]), fexp2(s1v[2 * tt + 1]));             \
    }                                                                             \
    _Pragma("unroll")                                                             \
    for (int tt = 0; tt < 4; ++tt) {                                              \
      lr0 = __builtin_amdgcn_fdot2(__builtin_bit_cast(f16x2, pk0[tt]),     one2, lr0, false); \
      lr1 = __builtin_amdgcn_fdot2(__builtin_bit_cast(f16x2, pk0[tt + 4]), one2, lr1, false); \
      lr2 = __builtin_amdgcn_fdot2(__builtin_bit_cast(f16x2, pk1[tt]),     one2, lr2, false); \
      lr3 = __builtin_amdgcn_fdot2(__builtin_bit_cast(f16x2, pk1[tt + 4]), one2, lr3, false); \
    }                                                                             \
    const f16x8 pb0 = mk8(pk0[0], pk0[1], pk0[2], pk0[3]);                        \
    const f16x8 pb1 = mk8(pk0[4], pk0[5], pk0[6], pk0[7]);                        \
    const f16x8 pb2 = mk8(pk1[0], pk1[1], pk1[2], pk1[3]);                        \
    const f16x8 pb3 = mk8(pk1[4], pk1[5], pk1[6], pk1[7]);                        \
    __builtin_amdgcn_s_setprio(1);                                                \
    oacc0 = __builtin_amdgcn_mfma_f32_32x32x16_f16(va0[0], pb0, oacc0, 0, 0, 0);  \
    oacc1 = __builtin_amdgcn_mfma_f32_32x32x16_f16(va1[0], pb0, oacc1, 0, 0, 0);  \
    oacc0 = __builtin_amdgcn_mfma_f32_32x32x16_f16(va0[1], pb1, oacc0, 0, 0, 0);  \
    oacc1 = __builtin_amdgcn_mfma_f32_32x32x16_f16(va1[1], pb1, oacc1, 0, 0, 0);  \
    oacc0 = __builtin_amdgcn_mfma_f32_32x32x16_f16(va0[2], pb2, oacc0, 0, 0, 0);  \
    oacc1 = __builtin_amdgcn_mfma_f32_32x32x16_f16(va1[2], pb2, oacc1, 0, 0, 0);  \
    oacc0 = __builtin_amdgcn_mfma_f32_32x32x16_f16(va0[3], pb3, oacc0, 0, 0, 0);  \
    oacc1 = __builtin_amdgcn_mfma_f32_32x32x16_f16(va1[3], pb3, oacc1, 0, 0, 0);  \
    __builtin_amdgcn_s_setprio(0);                                                \
  } while (0)

__global__ __launch_bounds__(256, 3)
void attn_fused11(const ushort_t* __restrict__ qb, const ushort_t* __restrict__ kb,
                  const ushort_t* __restrict__ vt, ushort_t* __restrict__ ao) {
  __shared__ __align__(16) ushort_t asmem[16384];  // K dbuf 16KB + V dbuf 16KB
  const int tid = threadIdx.x;
  const int w = tid >> 6, l = tid & 63;
  const int lq = l & 31, hi = l >> 5;

  const int bid = blockIdx.x;
  const int cid = (bid & 7) * 96 + (bid >> 3);
  const int bh = cid >> 3, qt = cid & 7;
  const int b = bh / 12, h = bh % 12;

  // Q: granule-major B-frags, one 1KB burst per kc
  const ushort_t* qp = qb + ((size_t)(bh * 32 + qt * 4 + w)) * 2048;
  const ushort_t* kp = kb + (size_t)bh * 65536;
  const ushort_t* vp = vt + (size_t)bh * 65536;

  f16x8 qf[4];
#pragma unroll
  for (int kc = 0; kc < 4; ++kc)
    qf[kc] = *(const f16x8*)(qp + kc * 512 + l * 8);

  char* Kl0 = (char*)asmem + w * 1024;            // + buf*8192; dest chunk = tid
  char* Kl1 = (char*)asmem + 4096 + w * 1024;     // dest chunk = tid+256
  char* Vl0 = (char*)asmem + 16384 + w * 1024;
  char* Vl1 = (char*)asmem + 16384 + 4096 + w * 1024;

  f32x16 oacc0 = {}, oacc1 = {};
  float lr0 = 0.f, lr1 = 0.f, lr2 = 0.f, lr3 = 0.f;
  const f16x2 one2 = {(_Float16)1.f, (_Float16)1.f};

  // prologue: stage tile 0 (linear granule copy)
  gload_lds16(kp + tid * 8,         Kl0);
  gload_lds16(kp + (tid + 256) * 8, Kl1);
  gload_lds16(vp + tid * 8,         Vl0);
  gload_lds16(vp + (tid + 256) * 8, Vl1);

  for (int t2 = 0; t2 < 16; t2 += 2) {
    ATILE(t2, 0, 1);
    ATILE(t2 + 1, 1, 0);
  }

  float lrun = (lr0 + lr1) + (lr2 + lr3);
  lrun += __shfl_xor(lrun, 32, 64);
  const float invl = 1.0f / lrun;

  __syncthreads();   // full drain before smem reuse (once, outside loop)

  // ---- epilogue: O^T -> swizzled LDS -> fragment-major aout granules ----
  uint_t* ot = (uint_t*)asmem + w * 1024 + lq * 32;
#pragma unroll
  for (int tt = 0; tt < 8; ++tt) {
    const int base = (tt & 1) + ((tt >> 1) << 2) + 2 * hi;
    ot[base ^ lq]        = packpair(oacc0[2 * tt] * invl, oacc0[2 * tt + 1] * invl);
    ot[(base + 16) ^ lq] = packpair(oacc1[2 * tt] * invl, oacc1[2 * tt + 1] * invl);
  }
  __syncthreads();
  const int row = tid >> 1, halfc = tid & 1;        // row 0..127
  const int w2 = row >> 5, qq = row & 31;
  const uint_t* srcp = (const uint_t*)asmem + w2 * 1024 + qq * 32;
  const int m = b * 1024 + qt * 128 + row;
  const int panel = m >> 4, lrr = m & 15;
  const int kc = h * 2 + halfc;
#pragma unroll
  for (int jj = 0; jj < 4; ++jj) {
    u32x4 tv;
#pragma unroll
    for (int i2 = 0; i2 < 4; ++i2)
      tv[i2] = srcp[(halfc * 16 + jj * 4 + i2) ^ qq];
    *(u32x4*)(ao + ((size_t)((panel * 24 + kc) * 64 + jj * 16 + lrr)) * 8) = tv;
  }
}

// ---------- launch ----------
extern "C" void kernel_launch(void* const* d_in, const int* in_sizes, int n_in,
                              void* d_out, int out_size, void* d_ws, size_t ws_size,
                              hipStream_t stream) {
  const float* x  = (const float*)d_in[0];
  const float* nw = (const float*)d_in[1];
  const float* wq = (const float*)d_in[2];
  const float* bq = (const float*)d_in[3];
  const float* wk = (const float*)d_in[4];
  const float* bk = (const float*)d_in[5];
  const float* wv = (const float*)d_in[6];
  const float* bv = (const float*)d_in[7];
  const float* wo = (const float*)d_in[8];
  const float* bo = (const float*)d_in[9];
  float* out = (float*)d_out;

  char* ws = (char*)d_ws;
  // tmp (12.58MB f16) is consumed by lrn_b, then its region is reused for qbuf.
  ushort_t* tmp   = (ushort_t*)ws;
  ushort_t* qbuf  = (ushort_t*)(ws);
  ushort_t* kbuf  = (ushort_t*)(ws + 12582912);
  ushort_t* xnf   = (ushort_t*)(ws + 25165824);   // 12,582,912 (fragment-major)
  ushort_t* bwqkv = (ushort_t*)(ws + 37748736);   //  3,538,944 (fragment-major)
  ushort_t* bwo   = (ushort_t*)(ws + 41287680);   //  1,179,648 (fragment-major)
  ushort_t* vtb   = (ushort_t*)(ws + 42467328);   // 12,582,912 (granule-major)
  ushort_t* aoutf = (ushort_t*)(ws + 55050240);   // 12,582,912 (fragment-major)

  lrn_a<<<6144, 256, 0, stream>>>(x, tmp);
  lrn_b<<<6144, 256, 0, stream>>>(x, tmp, nw, xnf);
  convw_fm<<<1152, 256, 0, stream>>>(wq, wk, wv, wo, bwqkv, bwo);
  gemm_lds<0><<<1152, 256, 0, stream>>>(xnf, bwqkv, bq, bk, bv,
                                        qbuf, kbuf, vtb, nullptr);
  attn_fused11<<<768, 256, 0, stream>>>(qbuf, kbuf, vtb, aoutf);
  gemm_lds<1><<<768, 256, 0, stream>>>(aoutf, bwo, bo, nullptr, nullptr,
                                       nullptr, nullptr, nullptr, out);
}

// Round 16
// 134.668 us; speedup vs baseline: 1.0244x; 1.0244x over previous
//
#include <hip/hip_runtime.h>

// ---------- types ----------
typedef _Float16 f16x8 __attribute__((ext_vector_type(8)));
typedef _Float16 f16x4 __attribute__((ext_vector_type(4)));
typedef _Float16 f16x2 __attribute__((ext_vector_type(2)));
typedef float    f32x4 __attribute__((ext_vector_type(4)));
typedef float    f32x16 __attribute__((ext_vector_type(16)));
typedef unsigned int u32x4 __attribute__((ext_vector_type(4)));
typedef unsigned short ushort_t;
typedef unsigned int uint_t;

#define LOG2E 1.44269504088896340736f

// counted-wait / barrier primitives (T4: loads stay in flight across barriers)
#define CFENCE  asm volatile("" ::: "memory")
#define HWBAR   __builtin_amdgcn_s_barrier()
#define VMCNT0  asm volatile("s_waitcnt vmcnt(0)" ::: "memory")
#define VMCNT3  asm volatile("s_waitcnt vmcnt(3)" ::: "memory")
#define VMCNT4  asm volatile("s_waitcnt vmcnt(4)" ::: "memory")

__device__ __forceinline__ ushort_t f2h(float x) {
  _Float16 h = (_Float16)x;
  return __builtin_bit_cast(ushort_t, h);
}

// raw v_exp_f32 (skips LLVM denormal-guard expansion; inputs in [-30,15]).
__device__ __forceinline__ float fexp2(float x) {
#if __has_builtin(__builtin_amdgcn_exp2f)
  return __builtin_amdgcn_exp2f(x);
#else
  float r; asm("v_exp_f32 %0, %1" : "=v"(r) : "v"(x)); return r;
#endif
}

// raw v_rsq_f32.
__device__ __forceinline__ float frsq(float x) {
#if __has_builtin(__builtin_amdgcn_rsqf)
  return __builtin_amdgcn_rsqf(x);
#else
  float r; asm("v_rsq_f32 %0, %1" : "=v"(r) : "v"(x)); return r;
#endif
}

__device__ __forceinline__ uint_t packpair(float a, float b) {
  return __builtin_bit_cast(uint_t, __builtin_amdgcn_cvt_pkrtz(a, b));
}

__device__ __forceinline__ f16x8 mk8(uint_t a, uint_t b, uint_t c, uint_t d) {
  u32x4 t; t[0] = a; t[1] = b; t[2] = c; t[3] = d;
  return __builtin_bit_cast(f16x8, t);
}

// async global->LDS, 16B per lane; LDS dest wave-uniform base + lane*16.
__device__ __forceinline__ void gload_lds16(const void* g, void* lds) {
  __builtin_amdgcn_global_load_lds(
      (const __attribute__((address_space(1))) void*)(uintptr_t)g,
      (__attribute__((address_space(3))) void*)(unsigned)(uintptr_t)lds,
      16, 0, 0);
}

// Fragment-major ("fm") for the GEMMs: granule (panel,kc) = 16 rows x K=32,
//   fm[(panel*24 + kc)*64 + l] (16B) = M[panel*16 + (l&15)][kc*32 + (l>>4)*8..+7]
// Granule-major for attention (32x32x16 frags, 1KB granules, lane-exact):
//   qbuf : [bh][qpanel 0..31][kch 0..3]   B-frag: lane = (q&31) + 32*((d>>3)&1)
//   kbuf : [bh][tile 0..15][rowp*4+dch]   A-frag: lane = (kv&31) + 32*((d>>3)&1)
//   vtb  : [bh][tile 0..15][dp*4+chunk]   A-frag: lane = (d&31) + 32*((slot>>3)&1)

// ---------- LocalRmsNorm: pass A (horizontal 7-tap box of x^2) -> f16 tmp ----------
__global__ __launch_bounds__(256)
void lrn_a(const float* __restrict__ x, ushort_t* __restrict__ tmp) {
  int tid = blockIdx.x * 256 + threadIdx.x;     // 8*1024*192 threads
  int dv  = tid % 192;
  int rem = tid / 192;
  int pos = rem & 1023;
  int b   = rem >> 10;
  int r = pos >> 5, c = pos & 31;
  const float4* base = (const float4*)x + ((size_t)b * 1024 + (size_t)r * 32) * 192 + dv;
  float ax = 0.f, ay = 0.f, az = 0.f, aw = 0.f;
#pragma unroll
  for (int dc = -3; dc <= 3; ++dc) {
    int cc = c + dc;
    if (cc >= 0 && cc < 32) {
      float4 v = base[cc * 192];
      ax += v.x * v.x; ay += v.y * v.y; az += v.z * v.z; aw += v.w * v.w;
    }
  }
  f16x4 o;
  o[0] = (_Float16)ax; o[1] = (_Float16)ay; o[2] = (_Float16)az; o[3] = (_Float16)aw;
  *(f16x4*)(tmp + (size_t)tid * 4) = o;
}

// ---------- LocalRmsNorm: pass B (vertical 7-tap) -> xn (f16, FRAGMENT-MAJOR) ----------
__global__ __launch_bounds__(256)
void lrn_b(const float* __restrict__ x, const ushort_t* __restrict__ tmp,
           const float* __restrict__ wn, ushort_t* __restrict__ xn) {
  int tid = blockIdx.x * 256 + threadIdx.x;
  int dv  = tid % 192;
  int rem = tid / 192;
  int pos = rem & 1023;
  int b   = rem >> 10;
  int r = pos >> 5, c = pos & 31;
  const ushort_t* tb = tmp + (((size_t)b * 1024 + c) * 192 + dv) * 4;
  float ax = 0.f, ay = 0.f, az = 0.f, aw = 0.f;
#pragma unroll
  for (int dr = -3; dr <= 3; ++dr) {
    int rr = r + dr;
    if (rr >= 0 && rr < 32) {
      f16x4 v = *(const f16x4*)(tb + (size_t)rr * 24576);
      ax += (float)v[0]; ay += (float)v[1]; az += (float)v[2]; aw += (float)v[3];
    }
  }
  float4 xv = ((const float4*)x)[tid];
  float4 wv = ((const float4*)wn)[dv];
  const float inv49 = 1.0f / 49.0f;
  float i0 = frsq(1e-7f + ax * inv49);
  float i1 = frsq(1e-7f + ay * inv49);
  float i2 = frsq(1e-7f + az * inv49);
  float i3 = frsq(1e-7f + aw * inv49);
  f16x4 o;
  o[0] = (_Float16)(xv.x * i0 * wv.x);
  o[1] = (_Float16)(xv.y * i1 * wv.y);
  o[2] = (_Float16)(xv.z * i2 * wv.z);
  o[3] = (_Float16)(xv.w * i3 * wv.w);
  const int m = b * 1024 + pos;
  const int panel = m >> 4, lrr = m & 15;
  const int kc = dv >> 3, lg2 = (dv >> 1) & 3, half = dv & 1;
  *(f16x4*)(xn + ((size_t)((panel * 24 + kc) * 64 + lg2 * 16 + lrr)) * 8 + half * 4) = o;
}

// ---------- weight conversion f32 -> f16 fragment-major ----------
__global__ __launch_bounds__(256)
void convw_fm(const float* __restrict__ wq, const float* __restrict__ wk,
              const float* __restrict__ wv, const float* __restrict__ wo,
              ushort_t* __restrict__ bqkv, ushort_t* __restrict__ bwo) {
  const int g = blockIdx.x * 256 + threadIdx.x;   // 294912 total
  const int mat = g / 73728;
  const int gg = g % 73728;
  const int panel = gg / 1536;
  const int rem = gg % 1536;
  const int kc = rem >> 6, l = rem & 63;
  const int row = panel * 16 + (l & 15);
  const int col = kc * 32 + (l >> 4) * 8;
  const float* src = (mat == 0) ? wq : (mat == 1) ? wk : (mat == 2) ? wv : wo;
  const float4 v0 = *(const float4*)(src + (size_t)row * 768 + col);
  const float4 v1 = *(const float4*)(src + (size_t)row * 768 + col + 4);
  f16x8 o;
  o[0]=(_Float16)v0.x; o[1]=(_Float16)v0.y; o[2]=(_Float16)v0.z; o[3]=(_Float16)v0.w;
  o[4]=(_Float16)v1.x; o[5]=(_Float16)v1.y; o[6]=(_Float16)v1.z; o[7]=(_Float16)v1.w;
  if (mat < 3) *(f16x8*)(bqkv + (size_t)g * 8) = o;
  else         *(f16x8*)(bwo  + (size_t)gg * 8) = o;
}

// ---------- GEMM: fm-granule LDS staging + counted-vmcnt (r8-proven protocol) ----------
// MODE 0: 8 waves (512 thr), block 128x256 (PM=8, PN=16), grid 64x9=576
//         (2.25 blk/CU, 48KB LDS -> up to 3 resident) -> Q/K/V granule scatter.
// MODE 1: 4 waves (256 thr), block 64x128 (PM=4, PN=8), grid 128x6=768.
// Both: SI=3 stage instrs/wave, 2 barriers/K-step, stage(kt+1) in flight
// across both barriers (counted VMCNT3, never 0 in-loop).
#define GSTAGE(BUF, KT) do {                                                      \
    _Pragma("unroll")                                                             \
    for (int j = 0; j < SI; ++j)                                                  \
      gload_lds16(sb[j] + (KT) * 512, (BUF) ? d1[j] : d0[j]);                     \
  } while (0)

#define GTILE(KT, CUR, NXT) do {                                                  \
    CFENCE; HWBAR; CFENCE;                    /* prev-tile reads done */          \
    if ((KT) + 1 < 24) {                                                          \
      GSTAGE(NXT, (KT) + 1);                                                      \
      VMCNT3;                                 /* kt's granules landed */          \
    } else VMCNT0;                                                                \
    CFENCE; HWBAR;                            /* all waves' kt data visible */    \
    __builtin_amdgcn_sched_barrier(0);                                            \
    f16x8 af[MT], bf[NT];                                                         \
    _Pragma("unroll")                                                             \
    for (int mt = 0; mt < MT; ++mt)                                               \
      af[mt] = *(const f16x8*)(&As[CUR][(wr * MT + mt) * 512 + l * 8]);           \
    _Pragma("unroll")                                                             \
    for (int nt = 0; nt < NT; ++nt)                                               \
      bf[nt] = *(const f16x8*)(&Bs[CUR][(wc * NT + nt) * 512 + l * 8]);           \
    _Pragma("unroll")                                                             \
    for (int mt = 0; mt < MT; ++mt)                                               \
      _Pragma("unroll")                                                           \
      for (int nt = 0; nt < NT; ++nt)                                             \
        acc[mt][nt] = __builtin_amdgcn_mfma_f32_16x16x32_f16(af[mt], bf[nt], acc[mt][nt], 0, 0, 0); \
  } while (0)

template <int MODE>
__global__ __launch_bounds__(MODE == 0 ? 512 : 256)
void gemm_lds(const ushort_t* __restrict__ Afm, const ushort_t* __restrict__ Bfm,
              const float* __restrict__ b0, const float* __restrict__ b1,
              const float* __restrict__ b2,
              ushort_t* __restrict__ q, ushort_t* __restrict__ k,
              ushort_t* __restrict__ v, float* __restrict__ outf) {
  constexpr int NW  = (MODE == 0) ? 8 : 4;     // waves per block
  constexpr int PM  = (MODE == 0) ? 8 : 4;     // A panels (16 rows each)
  constexpr int PN  = (MODE == 0) ? 16 : 8;    // B panels
  constexpr int NBN = (MODE == 0) ? 9 : 6;
  constexpr int SI  = (PM + PN) / NW;          // = 3 in both modes
  constexpr int MT  = PM / 2;                  // m-frags per wave (4 / 2)
  constexpr int NT  = 4;                       // n-frags per wave
  __shared__ __align__(16) ushort_t As[2][PM * 512];
  __shared__ __align__(16) ushort_t Bs[2][PN * 512];

  const int nwg = gridDim.x;
  const int bid = blockIdx.x;
  const int cid = (bid & 7) * (nwg >> 3) + (bid >> 3);   // XCD-contiguous
  const int bm = cid / NBN, bn = cid % NBN;
  const int tid = threadIdx.x;
  const int w = tid >> 6, l = tid & 63;
  const int wr = (MODE == 0) ? (w >> 2) : (w >> 1);      // 0..1
  const int wc = (MODE == 0) ? (w & 3) : (w & 1);        // 0..3 / 0..1
  const int lr = l & 15, lg = l >> 4;

  f32x4 acc[MT][NT] = {};

  // per-wave stage assignments: granule g = w*SI + j (A: 0..PM-1, B: PM..)
  const ushort_t* sb[SI];
  ushort_t* d0[SI];
  ushort_t* d1[SI];
#pragma unroll
  for (int j = 0; j < SI; ++j) {
    const int g = w * SI + j;
    if (g < PM) {
      sb[j] = Afm + ((size_t)(bm * PM + g) * 24) * 512 + l * 8;
      d0[j] = &As[0][g * 512]; d1[j] = &As[1][g * 512];
    } else {
      sb[j] = Bfm + ((size_t)(bn * PN + (g - PM)) * 24) * 512 + l * 8;
      d0[j] = &Bs[0][(g - PM) * 512]; d1[j] = &Bs[1][(g - PM) * 512];
    }
  }

  GSTAGE(0, 0);
  for (int kt = 0; kt < 24; kt += 2) {
    GTILE(kt, 0, 1);
    GTILE(kt + 1, 1, 0);
  }

  // epilogue. C/D 16x16: col = lane&15, row = (lane>>4)*4 + reg  [m89/m91]
  constexpr int BNW = (MODE == 0) ? 256 : 128;   // block n-width
#pragma unroll
  for (int mt = 0; mt < MT; ++mt) {
#pragma unroll
    for (int nt = 0; nt < NT; ++nt) {
      if (MODE == 0) {
        const int n = bn * BNW + wc * 64 + nt * 16 + lr;
        const int mbase = bm * 128 + wr * 64 + mt * 16 + lg * 4;
        const int region = n / 768;          // uniform per block (768%256==0)
        const int nn = n - region * 768;
        const int hh = nn >> 6, hd = nn & 63;
        const float bb = (region == 0 ? b0 : region == 1 ? b1 : b2)[nn];
        const int khalf = (hd >> 3) & 1, kch = hd >> 4, jd = hd & 7;
        if (region == 2) {
          // V^T granule-major with sigma^{-1} kv-slot mapping (PV k-order)
          const int bi = mbase >> 10, s0 = mbase & 1023;
          const int tile = s0 >> 6, q6 = s0 & 63;
          const int aa = q6 >> 5, r5 = q6 & 31;
          const int t1 = r5 >> 3, h2 = (r5 >> 2) & 1;
          const int gq = t1 >> 1, jj = (2 * t1) & 3;
          const int chunk = (aa << 1) + gq;           // slot>>4
          const int gidx = (hd >> 5) * 4 + chunk;
          const int lane = (hd & 31) + 32 * h2;
          f16x4 pv;
#pragma unroll
          for (int gi = 0; gi < 4; ++gi) pv[gi] = (_Float16)(acc[mt][nt][gi] + bb);
          *(f16x4*)(v + (((size_t)(bi * 12 + hh) * 16 + tile) * 8 + gidx) * 512
                      + lane * 8 + 2 * jj) = pv;
        } else {
#pragma unroll
          for (int gi = 0; gi < 4; ++gi) {
            const int m = mbase + gi;
            const int bi = m >> 10, s = m & 1023;
            const float val = acc[mt][nt][gi] + bb;
            if (region == 0) {
              // Q granule-major B-frag: lane = (s&31) + 32*khalf
              const int lane = (s & 31) + 32 * khalf;
              q[(((size_t)(bi * 12 + hh) * 32 + (s >> 5)) * 4 + kch) * 512
                + lane * 8 + jd] = f2h(val * (0.125f * LOG2E));
            } else {
              // K granule-major A-frag: granule = rowp*4 + dch
              const int lane = (s & 31) + 32 * khalf;
              k[(((size_t)(bi * 12 + hh) * 16 + (s >> 6)) * 8
                 + ((s >> 5) & 1) * 4 + kch) * 512 + lane * 8 + jd] = f2h(val);
            }
          }
        }
      } else {
        const int n = bn * BNW + wc * 64 + nt * 16 + lr;
        const float bb = b0[n];
#pragma unroll
        for (int gi = 0; gi < 4; ++gi) {
          const int m = bm * 64 + wr * 32 + mt * 16 + lg * 4 + gi;
          outf[(size_t)m * 768 + n] = acc[mt][nt][gi] + bb;
        }
      }
    }
  }
}

// ---------- fused flash attention: granule-major K/V/Q, conflict-free LDS ----------
#define ATILE(T, CUR, NXT) do {                                                   \
    CFENCE; HWBAR; CFENCE;                   /* prev-tile reads done */           \
    if ((T) < 15) {                                                               \
      const ushort_t* ksrc = kp + (size_t)((T) + 1) * 4096;                       \
      const ushort_t* vsrc = vp + (size_t)((T) + 1) * 4096;                       \
      gload_lds16(ksrc + tid * 8,           Kl0 + (NXT) * 8192);                  \
      gload_lds16(ksrc + (tid + 256) * 8,   Kl1 + (NXT) * 8192);                  \
      gload_lds16(vsrc + tid * 8,           Vl0 + (NXT) * 8192);                  \
      gload_lds16(vsrc + (tid + 256) * 8,   Vl1 + (NXT) * 8192);                  \
      VMCNT4;                                /* tile T's 4 loads landed */        \
    } else VMCNT0;                                                                \
    CFENCE; HWBAR;                           /* all waves' tile-T data visible */ \
    __builtin_amdgcn_sched_barrier(0);                                            \
    const char* kbase = (const char*)asmem + (CUR) * 8192;                        \
    const char* vbase = (const char*)asmem + 16384 + (CUR) * 8192;                \
    f16x8 ka0[4], ka1[4];                                                         \
    _Pragma("unroll")                                                             \
    for (int kc = 0; kc < 4; ++kc) {                                              \
      ka0[kc] = *(const f16x8*)(kbase + kc * 1024 + l * 16);                      \
      ka1[kc] = *(const f16x8*)(kbase + 4096 + kc * 1024 + l * 16);               \
    }                                                                             \
    f32x16 s0v = {}, s1v = {};                                                    \
    __builtin_amdgcn_s_setprio(1);                                                \
    _Pragma("unroll")                                                             \
    for (int kc = 0; kc < 4; ++kc) {                                              \
      s0v = __builtin_amdgcn_mfma_f32_32x32x16_f16(ka0[kc], qf[kc], s0v, 0, 0, 0);\
      s1v = __builtin_amdgcn_mfma_f32_32x32x16_f16(ka1[kc], qf[kc], s1v, 0, 0, 0);\
    }                                                                             \
    __builtin_amdgcn_s_setprio(0);                                                \
    f16x8 va0[4], va1[4];                                                         \
    _Pragma("unroll")                                                             \
    for (int c = 0; c < 4; ++c) {                                                 \
      va0[c] = *(const f16x8*)(vbase + c * 1024 + l * 16);                        \
      va1[c] = *(const f16x8*)(vbase + 4096 + c * 1024 + l * 16);                 \
    }                                                                             \
    uint_t pk0[8], pk1[8];                                                        \
    _Pragma("unroll")                                                             \
    for (int tt = 0; tt < 8; ++tt) {                                              \
      pk0[tt] = packpair(fexp2(s0v[2 * tt]), fexp2(s0v[2 * tt + 1]));             \
      pk1[tt] = packpair(fexp2(s1v[2 * tt]), fexp2(s1v[2 * tt + 1]));             \
    }                                                                             \
    _Pragma("unroll")                                                             \
    for (int tt = 0; tt < 4; ++tt) {                                              \
      lr0 = __builtin_amdgcn_fdot2(__builtin_bit_cast(f16x2, pk0[tt]),     one2, lr0, false); \
      lr1 = __builtin_amdgcn_fdot2(__builtin_bit_cast(f16x2, pk0[tt + 4]), one2, lr1, false); \
      lr2 = __builtin_amdgcn_fdot2(__builtin_bit_cast(f16x2, pk1[tt]),     one2, lr2, false); \
      lr3 = __builtin_amdgcn_fdot2(__builtin_bit_cast(f16x2, pk1[tt + 4]), one2, lr3, false); \
    }                                                                             \
    const f16x8 pb0 = mk8(pk0[0], pk0[1], pk0[2], pk0[3]);                        \
    const f16x8 pb1 = mk8(pk0[4], pk0[5], pk0[6], pk0[7]);                        \
    const f16x8 pb2 = mk8(pk1[0], pk1[1], pk1[2], pk1[3]);                        \
    const f16x8 pb3 = mk8(pk1[4], pk1[5], pk1[6], pk1[7]);                        \
    __builtin_amdgcn_s_setprio(1);                                                \
    oacc0 = __builtin_amdgcn_mfma_f32_32x32x16_f16(va0[0], pb0, oacc0, 0, 0, 0);  \
    oacc1 = __builtin_amdgcn_mfma_f32_32x32x16_f16(va1[0], pb0, oacc1, 0, 0, 0);  \
    oacc0 = __builtin_amdgcn_mfma_f32_32x32x16_f16(va0[1], pb1, oacc0, 0, 0, 0);  \
    oacc1 = __builtin_amdgcn_mfma_f32_32x32x16_f16(va1[1], pb1, oacc1, 0, 0, 0);  \
    oacc0 = __builtin_amdgcn_mfma_f32_32x32x16_f16(va0[2], pb2, oacc0, 0, 0, 0);  \
    oacc1 = __builtin_amdgcn_mfma_f32_32x32x16_f16(va1[2], pb2, oacc1, 0, 0, 0);  \
    oacc0 = __builtin_amdgcn_mfma_f32_32x32x16_f16(va0[3], pb3, oacc0, 0, 0, 0);  \
    oacc1 = __builtin_amdgcn_mfma_f32_32x32x16_f16(va1[3], pb3, oacc1, 0, 0, 0);  \
    __builtin_amdgcn_s_setprio(0);                                                \
  } while (0)

__global__ __launch_bounds__(256, 3)
void attn_fused11(const ushort_t* __restrict__ qb, const ushort_t* __restrict__ kb,
                  const ushort_t* __restrict__ vt, ushort_t* __restrict__ ao) {
  __shared__ __align__(16) ushort_t asmem[16384];  // K dbuf 16KB + V dbuf 16KB
  const int tid = threadIdx.x;
  const int w = tid >> 6, l = tid & 63;
  const int lq = l & 31, hi = l >> 5;

  const int bid = blockIdx.x;
  const int cid = (bid & 7) * 96 + (bid >> 3);
  const int bh = cid >> 3, qt = cid & 7;
  const int b = bh / 12, h = bh % 12;

  // Q: granule-major B-frags, one 1KB burst per kc
  const ushort_t* qp = qb + ((size_t)(bh * 32 + qt * 4 + w)) * 2048;
  const ushort_t* kp = kb + (size_t)bh * 65536;
  const ushort_t* vp = vt + (size_t)bh * 65536;

  f16x8 qf[4];
#pragma unroll
  for (int kc = 0; kc < 4; ++kc)
    qf[kc] = *(const f16x8*)(qp + kc * 512 + l * 8);

  char* Kl0 = (char*)asmem + w * 1024;            // + buf*8192; dest chunk = tid
  char* Kl1 = (char*)asmem + 4096 + w * 1024;     // dest chunk = tid+256
  char* Vl0 = (char*)asmem + 16384 + w * 1024;
  char* Vl1 = (char*)asmem + 16384 + 4096 + w * 1024;

  f32x16 oacc0 = {}, oacc1 = {};
  float lr0 = 0.f, lr1 = 0.f, lr2 = 0.f, lr3 = 0.f;
  const f16x2 one2 = {(_Float16)1.f, (_Float16)1.f};

  // prologue: stage tile 0 (linear granule copy)
  gload_lds16(kp + tid * 8,         Kl0);
  gload_lds16(kp + (tid + 256) * 8, Kl1);
  gload_lds16(vp + tid * 8,         Vl0);
  gload_lds16(vp + (tid + 256) * 8, Vl1);

  for (int t2 = 0; t2 < 16; t2 += 2) {
    ATILE(t2, 0, 1);
    ATILE(t2 + 1, 1, 0);
  }

  float lrun = (lr0 + lr1) + (lr2 + lr3);
  lrun += __shfl_xor(lrun, 32, 64);
  const float invl = 1.0f / lrun;

  __syncthreads();   // full drain before smem reuse (once, outside loop)

  // ---- epilogue: O^T -> swizzled LDS -> fragment-major aout granules ----
  uint_t* ot = (uint_t*)asmem + w * 1024 + lq * 32;
#pragma unroll
  for (int tt = 0; tt < 8; ++tt) {
    const int base = (tt & 1) + ((tt >> 1) << 2) + 2 * hi;
    ot[base ^ lq]        = packpair(oacc0[2 * tt] * invl, oacc0[2 * tt + 1] * invl);
    ot[(base + 16) ^ lq] = packpair(oacc1[2 * tt] * invl, oacc1[2 * tt + 1] * invl);
  }
  __syncthreads();
  const int row = tid >> 1, halfc = tid & 1;        // row 0..127
  const int w2 = row >> 5, qq = row & 31;
  const uint_t* srcp = (const uint_t*)asmem + w2 * 1024 + qq * 32;
  const int m = b * 1024 + qt * 128 + row;
  const int panel = m >> 4, lrr = m & 15;
  const int kc = h * 2 + halfc;
#pragma unroll
  for (int jj = 0; jj < 4; ++jj) {
    u32x4 tv;
#pragma unroll
    for (int i2 = 0; i2 < 4; ++i2)
      tv[i2] = srcp[(halfc * 16 + jj * 4 + i2) ^ qq];
    *(u32x4*)(ao + ((size_t)((panel * 24 + kc) * 64 + jj * 16 + lrr)) * 8) = tv;
  }
}

// ---------- launch ----------
extern "C" void kernel_launch(void* const* d_in, const int* in_sizes, int n_in,
                              void* d_out, int out_size, void* d_ws, size_t ws_size,
                              hipStream_t stream) {
  const float* x  = (const float*)d_in[0];
  const float* nw = (const float*)d_in[1];
  const float* wq = (const float*)d_in[2];
  const float* bq = (const float*)d_in[3];
  const float* wk = (const float*)d_in[4];
  const float* bk = (const float*)d_in[5];
  const float* wv = (const float*)d_in[6];
  const float* bv = (const float*)d_in[7];
  const float* wo = (const float*)d_in[8];
  const float* bo = (const float*)d_in[9];
  float* out = (float*)d_out;

  char* ws = (char*)d_ws;
  // tmp (12.58MB f16) is consumed by lrn_b, then its region is reused for qbuf.
  ushort_t* tmp   = (ushort_t*)ws;
  ushort_t* qbuf  = (ushort_t*)(ws);
  ushort_t* kbuf  = (ushort_t*)(ws + 12582912);
  ushort_t* xnf   = (ushort_t*)(ws + 25165824);   // 12,582,912 (fragment-major)
  ushort_t* bwqkv = (ushort_t*)(ws + 37748736);   //  3,538,944 (fragment-major)
  ushort_t* bwo   = (ushort_t*)(ws + 41287680);   //  1,179,648 (fragment-major)
  ushort_t* vtb   = (ushort_t*)(ws + 42467328);   // 12,582,912 (granule-major)
  ushort_t* aoutf = (ushort_t*)(ws + 55050240);   // 12,582,912 (fragment-major)

  lrn_a<<<6144, 256, 0, stream>>>(x, tmp);
  lrn_b<<<6144, 256, 0, stream>>>(x, tmp, nw, xnf);
  convw_fm<<<1152, 256, 0, stream>>>(wq, wk, wv, wo, bwqkv, bwo);
  gemm_lds<0><<<576, 512, 0, stream>>>(xnf, bwqkv, bq, bk, bv,
                                       qbuf, kbuf, vtb, nullptr);
  attn_fused11<<<768, 256, 0, stream>>>(qbuf, kbuf, vtb, aoutf);
  gemm_lds<1><<<768, 256, 0, stream>>>(aoutf, bwo, bo, nullptr, nullptr,
                                       nullptr, nullptr, nullptr, out);
}